// Round 20
// baseline (355.902 us; speedup 1.0000x reference)
//
#include <hip/hip_runtime.h>
#include <hip/hip_bf16.h>
#include <hip/hip_fp16.h>

#define N_NODES 50000
#define N_EDGES 800000
#define E_TOTAL (N_EDGES + N_NODES) /* 850000, self-loops appended */
#define BKT 96      /* fixed edge-bucket stride per dst; max degree ~45 << 96 */
#define NTILES 782  /* ceil(50000/64) gemm row-tiles */
#define EDGE_BLK4 ((E_TOTAL + 1023) / 1024) /* 831: 4 edges per thread */
#define ZERO_BLK ((N_NODES + 1023) / 1024)  /* 49: cursor zeroing in prep */

typedef _Float16 f16x8 __attribute__((ext_vector_type(8)));
typedef _Float16 f16x4 __attribute__((ext_vector_type(4)));
typedef float f32x4 __attribute__((ext_vector_type(4)));

// async global->LDS, 16B per lane, LDS dest = wave-uniform base + lane*16
__device__ __forceinline__ void gl_lds16(const _Float16* g, _Float16* l) {
  __builtin_amdgcn_global_load_lds(
      (const __attribute__((address_space(1))) unsigned int*)g,
      (__attribute__((address_space(3))) unsigned int*)l, 16, 0, 0);
}

// ---------------------------------------------------------------------------
// prep: 3 W transposes + cursor zeroing (replaces hipMemsetAsync node)
// ---------------------------------------------------------------------------
__global__ __launch_bounds__(256) void prep_kernel(
    const float* __restrict__ W0, const float* __restrict__ W1,
    const float* __restrict__ W2, _Float16* __restrict__ WT0,
    _Float16* __restrict__ WT1, _Float16* __restrict__ WT2,
    int* __restrict__ cursor) {
  __shared__ float tile[32][33];
  const int bid = blockIdx.x;
  if (bid < 192) {
    const float* W = (bid < 64) ? W0 : (bid < 128) ? W1 : W2;
    _Float16* WT = (bid < 64) ? WT0 : (bid < 128) ? WT1 : WT2;
    const int sub = bid & 63;
    const int bx = (sub & 7) * 32, by = (sub >> 3) * 32;
    const int tx = threadIdx.x & 31, ty = threadIdx.x >> 5;
#pragma unroll
    for (int i = 0; i < 32; i += 8)
      tile[ty + i][tx] = W[(size_t)(by + ty + i) * 256 + bx + tx];
    __syncthreads();
#pragma unroll
    for (int i = 0; i < 32; i += 8)
      WT[(size_t)(bx + ty + i) * 256 + by + tx] = (_Float16)tile[tx][ty + i];
  } else {
    int i = ((bid - 192) * 256 + threadIdx.x) * 4;
    if (i < N_NODES - 3) {
      *(int4*)&cursor[i] = make_int4(0, 0, 0, 0);
    } else {
      for (int j = i; j < N_NODES; j++)
        if (j >= i && j < i + 4) cursor[j] = 0;
    }
  }
}

// ---------------------------------------------------------------------------
// scatter: u16 bucket fill. 4 independent edge-chains per thread (ILP for a
// latency-bound kernel); regular stores (L2 write-allocate absorbs the
// partial-line RMW; nt-store measured no better in R19).
// ---------------------------------------------------------------------------
__global__ __launch_bounds__(256) void scatter_kernel(
    const int* __restrict__ ei, int* __restrict__ cursor,
    unsigned short* __restrict__ csr_src) {
  const int e0 = blockIdx.x * 1024 + threadIdx.x;
#pragma unroll
  for (int j = 0; j < 4; j++) {
    int e = e0 + j * 256;
    if (e < E_TOTAL) {
      int s, d;
      if (e < N_EDGES) {
        s = ei[e];
        d = ei[N_EDGES + e];
      } else {
        s = d = e - N_EDGES;
      }
      int pos = atomicAdd(&cursor[d], 1);
      csr_src[(size_t)d * BKT + pos] = (unsigned short)s;
    }
  }
}

// ---------------------------------------------------------------------------
// Fused MFMA GEMM + attention epilogue. AF16=false: A is f32 (layer 0);
// staged via reg-load -> (after MFMA cluster, latency hidden) cvt+ds_write.
// BM=64, BN=256, BK=32, 8 K-steps; 4 waves 2x2 (wave = 32x128 = 2x8 frags).
// B double-buffered via global_load_lds; stage k+1 issued before MFMA k.
// ---------------------------------------------------------------------------
template <int H, bool AF16>
__global__ __launch_bounds__(256) void gemm_att(
    const void* __restrict__ Ap, const _Float16* __restrict__ WT,
    const float* __restrict__ att_s, const float* __restrict__ att_d,
    _Float16* __restrict__ C, float* __restrict__ a_s, float* __restrict__ a_d,
    int M) {
  __shared__ _Float16 As[2][64 * 32];   // 4 KB each
  __shared__ _Float16 Bs[2][256 * 32];  // 16 KB each
  const _Float16* A16 = (const _Float16*)Ap;
  const float* A32 = (const float*)Ap;
  const int t = threadIdx.x, lane = t & 63, w = t >> 6;
  const int wr = w & 1, wc = w >> 1;
  const int row0 = blockIdx.x * 64;
  const int fr = lane & 15, fg = lane >> 4;
  const int srow = lane >> 2, sk = (lane & 3) * 8;
  const int arow = t >> 2, ak = (t & 3) * 8; // f32 A staging coords (256 thr)

  f32x4 acc[2][8] = {};
  int cur = 0;
  float4 ar0, ar1; // in-flight f32 A data (AF16=false)

#define STAGE_B(buf, k0)                                                      \
  do {                                                                        \
    gl_lds16(WT + (size_t)(w * 64 + srow) * 256 + (k0) + sk,                  \
             &Bs[buf][w * 2048]);                                             \
    gl_lds16(WT + (size_t)(w * 64 + 16 + srow) * 256 + (k0) + sk,             \
             &Bs[buf][w * 2048 + 512]);                                       \
    gl_lds16(WT + (size_t)(w * 64 + 32 + srow) * 256 + (k0) + sk,             \
             &Bs[buf][w * 2048 + 1024]);                                      \
    gl_lds16(WT + (size_t)(w * 64 + 48 + srow) * 256 + (k0) + sk,             \
             &Bs[buf][w * 2048 + 1536]);                                      \
  } while (0)

#define STAGE_A16(buf, k0)                                                    \
  gl_lds16(A16 + (size_t)(row0 + w * 16 + srow) * 256 + (k0) + sk,            \
           &As[buf][w * 512])

#define LOAD_A32(k0)                                                          \
  do {                                                                        \
    if (row0 + arow < M) {                                                    \
      ar0 = *(const float4*)(A32 + (size_t)(row0 + arow) * 256 + (k0) + ak);  \
      ar1 = *(const float4*)(A32 + (size_t)(row0 + arow) * 256 + (k0) + ak + 4);\
    } else {                                                                  \
      ar0 = make_float4(0.f, 0.f, 0.f, 0.f);                                  \
      ar1 = make_float4(0.f, 0.f, 0.f, 0.f);                                  \
    }                                                                         \
  } while (0)

#define WRITE_A32(buf)                                                        \
  do {                                                                        \
    f16x8 v;                                                                  \
    v[0] = (_Float16)ar0.x; v[1] = (_Float16)ar0.y;                           \
    v[2] = (_Float16)ar0.z; v[3] = (_Float16)ar0.w;                           \
    v[4] = (_Float16)ar1.x; v[5] = (_Float16)ar1.y;                           \
    v[6] = (_Float16)ar1.z; v[7] = (_Float16)ar1.w;                           \
    *(f16x8*)&As[buf][arow * 32 + ak] = v;                                    \
  } while (0)

  if constexpr (AF16) {
    STAGE_A16(0, 0);
  } else {
    LOAD_A32(0);
    WRITE_A32(0);
  }
  STAGE_B(0, 0);
  __syncthreads(); // stage 0 landed (vmcnt + lgkm drain)

  for (int kt = 0; kt < 8; kt++) {
    if (kt < 7) {
      if constexpr (AF16) STAGE_A16(cur ^ 1, (kt + 1) * 32);
      else LOAD_A32((kt + 1) * 32); // loads fly during MFMA below
      STAGE_B(cur ^ 1, (kt + 1) * 32);
    }
    f16x8 af[2], bf[8];
#pragma unroll
    for (int mi = 0; mi < 2; mi++)
      af[mi] = *(const f16x8*)&As[cur][(wr * 32 + mi * 16 + fr) * 32 + fg * 8];
#pragma unroll
    for (int ni = 0; ni < 8; ni++)
      bf[ni] = *(const f16x8*)&Bs[cur][(wc * 128 + ni * 16 + fr) * 32 + fg * 8];
#pragma unroll
    for (int mi = 0; mi < 2; mi++)
#pragma unroll
      for (int ni = 0; ni < 8; ni++)
        acc[mi][ni] = __builtin_amdgcn_mfma_f32_16x16x32_f16(af[mi], bf[ni], acc[mi][ni], 0, 0, 0);
    if constexpr (!AF16) {
      if (kt < 7) WRITE_A32(cur ^ 1); // f32 loads landed under MFMA
    }
    __syncthreads(); // drains vmcnt+lgkm: next stage complete, LDS reads done
    cur ^= 1;
  }
#undef STAGE_B
#undef STAGE_A16
#undef LOAD_A32
#undef WRITE_A32

  float as_c[8], ad_c[8];
#pragma unroll
  for (int ni = 0; ni < 8; ni++) {
    int c = wc * 128 + ni * 16 + fr;
    as_c[ni] = att_s[c];
    ad_c[ni] = att_d[c];
  }

#pragma unroll
  for (int mi = 0; mi < 2; mi++) {
#pragma unroll
    for (int reg = 0; reg < 4; reg++) {
      const int r = row0 + wr * 32 + mi * 16 + fg * 4 + reg;
      const bool valid = r < M;
      if (valid) {
#pragma unroll
        for (int ni = 0; ni < 8; ni++)
          C[(size_t)r * 256 + wc * 128 + ni * 16 + fr] = (_Float16)acc[mi][ni][reg];
      }
      float s0 = 0.f, s1 = 0.f, d0 = 0.f, d1 = 0.f;
#pragma unroll
      for (int ni = 0; ni < 4; ni++) {
        s0 = fmaf(acc[mi][ni][reg], as_c[ni], s0);
        d0 = fmaf(acc[mi][ni][reg], ad_c[ni], d0);
        s1 = fmaf(acc[mi][ni + 4][reg], as_c[ni + 4], s1);
        d1 = fmaf(acc[mi][ni + 4][reg], ad_c[ni + 4], d1);
      }
#pragma unroll
      for (int off = 1; off < 16; off <<= 1) {
        s0 += __shfl_xor(s0, off, 64);
        d0 += __shfl_xor(d0, off, 64);
        s1 += __shfl_xor(s1, off, 64);
        d1 += __shfl_xor(d1, off, 64);
      }
      if constexpr (H == 4) {
        if (fr == 0 && valid) {
          a_s[(size_t)r * 4 + wc * 2 + 0] = s0;
          a_s[(size_t)r * 4 + wc * 2 + 1] = s1;
          a_d[(size_t)r * 4 + wc * 2 + 0] = d0;
          a_d[(size_t)r * 4 + wc * 2 + 1] = d1;
        }
      } else {
        if (fr == 0) {
          float* L = (float*)As; // safe: last loop barrier covers LDS reads
          L[(r - row0) * 4 + wc * 2 + 0] = s0 + s1;
          L[(r - row0) * 4 + wc * 2 + 1] = d0 + d1;
        }
      }
    }
  }
  if constexpr (H == 1) {
    __syncthreads();
    float* L = (float*)As;
    if (t < 64 && row0 + t < M) {
      a_s[row0 + t] = L[t * 4 + 0] + L[t * 4 + 2];
      a_d[row0 + t] = L[t * 4 + 1] + L[t * 4 + 3];
    }
  }
}

// ---------------------------------------------------------------------------
// SINGLE-PASS segment softmax + weighted gather; u16 bucket edge list.
// ---------------------------------------------------------------------------
template <int H, bool ELU_OUT, bool OUT_F16>
__global__ __launch_bounds__(256, 8) void aggregate_kernel(
    const _Float16* __restrict__ XH16, const float* __restrict__ a_s,
    const float* __restrict__ a_d, const int* __restrict__ cursor,
    const unsigned short* __restrict__ csr_src, const float* __restrict__ bias,
    void* __restrict__ outp) {
  const int t = threadIdx.x;
  const int lane = t & 63, w = t >> 6;
  const int d = blockIdx.x * 4 + w;
  const size_t e0 = (size_t)d * BKT;
  const int deg = cursor[d];
  const int li = lane & 15;
  const int h4 = (H == 4) ? (lane >> 4) : 0;
  const float adv = (H == 4) ? a_d[(size_t)d * 4 + h4] : a_d[d];

  float dnp = 0.f;
  float acc0 = 0.f, acc1 = 0.f, acc2 = 0.f, acc3 = 0.f;
  for (int base = 0; base < deg; base += 16) {
    const int cnt = min(16, deg - base);
    int s_cur = 0;
    float p = 0.f;
    if (li < cnt) {
      s_cur = csr_src[e0 + base + li];
      float e = ((H == 4) ? a_s[(size_t)s_cur * 4 + h4] : a_s[s_cur]) + adv;
      e = e > 0.f ? e : 0.2f * e;
      p = __expf(e);
    }
    dnp += p;
#define GAT_BODY(j)                                                           \
  {                                                                           \
    int sj = __builtin_amdgcn_readfirstlane(__shfl(s_cur, (j), 64));          \
    float alj = __shfl(p, (lane & 48) + (j), 64);                             \
    f16x4 raw = *(const f16x4*)(XH16 + (size_t)sj * 256 + lane * 4);          \
    acc0 = fmaf(alj, (float)raw[0], acc0);                                    \
    acc1 = fmaf(alj, (float)raw[1], acc1);                                    \
    acc2 = fmaf(alj, (float)raw[2], acc2);                                    \
    acc3 = fmaf(alj, (float)raw[3], acc3);                                    \
  }
    if (cnt == 16) {
#pragma unroll
      for (int j = 0; j < 16; j++) GAT_BODY(j)
    } else {
      for (int j = 0; j < cnt; j++) GAT_BODY(j)
    }
#undef GAT_BODY
  }
#pragma unroll
  for (int off = 1; off < 16; off <<= 1) dnp += __shfl_xor(dnp, off, 64);
  const float inv = 1.f / (dnp + 1e-16f);

  float4 bv = *(const float4*)&bias[lane * 4];
  float v0 = fmaf(acc0, inv, bv.x), v1 = fmaf(acc1, inv, bv.y);
  float v2 = fmaf(acc2, inv, bv.z), v3 = fmaf(acc3, inv, bv.w);
  if constexpr (ELU_OUT) {
    v0 = v0 > 0.f ? v0 : (__expf(v0) - 1.f);
    v1 = v1 > 0.f ? v1 : (__expf(v1) - 1.f);
    v2 = v2 > 0.f ? v2 : (__expf(v2) - 1.f);
    v3 = v3 > 0.f ? v3 : (__expf(v3) - 1.f);
  }
  if constexpr (OUT_F16) {
    _Float16* out = (_Float16*)outp;
    f16x4 ov;
    ov[0] = (_Float16)v0; ov[1] = (_Float16)v1;
    ov[2] = (_Float16)v2; ov[3] = (_Float16)v3;
    *(f16x4*)(out + (size_t)d * 256 + lane * 4) = ov;
  } else {
    float* out = (float*)outp;
    *(float4*)(out + (size_t)d * 256 + lane * 4) = make_float4(v0, v1, v2, v3);
  }
}

// ---------------------------------------------------------------------------
extern "C" void kernel_launch(void* const* d_in, const int* in_sizes, int n_in,
                              void* d_out, int out_size, void* d_ws, size_t ws_size,
                              hipStream_t stream) {
  const float* x = (const float*)d_in[0];
  const int* ei = (const int*)d_in[1];
  const float* W0 = (const float*)d_in[2];
  const float* as0 = (const float*)d_in[3];
  const float* ad0 = (const float*)d_in[4];
  const float* b0 = (const float*)d_in[5];
  const float* W1 = (const float*)d_in[6];
  const float* as1 = (const float*)d_in[7];
  const float* ad1 = (const float*)d_in[8];
  const float* b1 = (const float*)d_in[9];
  const float* W2 = (const float*)d_in[10];
  const float* as2 = (const float*)d_in[11];
  const float* ad2 = (const float*)d_in[12];
  const float* b2 = (const float*)d_in[13];
  float* out = (float*)d_out;

  char* p = (char*)d_ws;
  _Float16* XH16 = (_Float16*)p;
  p += (size_t)N_NODES * 256 * 2; // 25.6 MB
  _Float16* H16 = (_Float16*)p;
  p += (size_t)N_NODES * 256 * 2; // 25.6 MB
  _Float16* WT0 = (_Float16*)p;
  p += 256 * 256 * 2;
  _Float16* WT1 = (_Float16*)p;
  p += 256 * 256 * 2;
  _Float16* WT2 = (_Float16*)p;
  p += 256 * 256 * 2;
  float* a_s = (float*)p;
  p += (size_t)N_NODES * 4 * 4;
  float* a_d = (float*)p;
  p += (size_t)N_NODES * 4 * 4;
  int* cursor = (int*)p;
  p += (size_t)N_NODES * 4;
  unsigned short* csr_src = (unsigned short*)p;
  p += (size_t)N_NODES * BKT * 2; // 9.6 MB u16 buckets

  // prep: W transposes + cursor zeroing (no separate memset node)
  prep_kernel<<<192 + ZERO_BLK, 256, 0, stream>>>(W0, W1, W2, WT0, WT1, WT2,
                                                  cursor);
  scatter_kernel<<<EDGE_BLK4, 256, 0, stream>>>(ei, cursor, csr_src);

  const int ngrid = N_NODES / 4; // 12500

  // layer 0 (A = f32 x, direct)
  gemm_att<4, false><<<NTILES, 256, 0, stream>>>(x, WT0, as0, ad0, XH16, a_s, a_d, N_NODES);
  aggregate_kernel<4, true, true><<<ngrid, 256, 0, stream>>>(
      XH16, a_s, a_d, cursor, csr_src, b0, H16);
  // layer 1
  gemm_att<4, true><<<NTILES, 256, 0, stream>>>(H16, WT1, as1, ad1, XH16, a_s, a_d, N_NODES);
  aggregate_kernel<4, true, true><<<ngrid, 256, 0, stream>>>(
      XH16, a_s, a_d, cursor, csr_src, b1, H16);
  // layer 2
  gemm_att<1, true><<<NTILES, 256, 0, stream>>>(H16, WT2, as2, ad2, XH16, a_s, a_d, N_NODES);
  aggregate_kernel<1, false, false><<<ngrid, 256, 0, stream>>>(
      XH16, a_s, a_d, cursor, csr_src, b2, out);
}

// Round 21
// 344.364 us; speedup vs baseline: 1.0335x; 1.0335x over previous
//
#include <hip/hip_runtime.h>
#include <hip/hip_bf16.h>
#include <hip/hip_fp16.h>

#define N_NODES 50000
#define N_EDGES 800000
#define E_TOTAL (N_EDGES + N_NODES) /* 850000, self-loops appended */
#define BKT 96      /* fixed edge-bucket stride per dst; max degree ~45 << 96 */
#define NTILES 782  /* ceil(50000/64) gemm row-tiles */
#define EDGE_BLK ((E_TOTAL + 255) / 256) /* 3321: 1 edge per thread */

typedef _Float16 f16x8 __attribute__((ext_vector_type(8)));
typedef _Float16 f16x4 __attribute__((ext_vector_type(4)));
typedef float f32x4 __attribute__((ext_vector_type(4)));

// async global->LDS, 16B per lane, LDS dest = wave-uniform base + lane*16
__device__ __forceinline__ void gl_lds16(const _Float16* g, _Float16* l) {
  __builtin_amdgcn_global_load_lds(
      (const __attribute__((address_space(1))) unsigned int*)g,
      (__attribute__((address_space(3))) unsigned int*)l, 16, 0, 0);
}

// ---------------------------------------------------------------------------
// prep_scatter: u16 bucket scatter (1 edge/thread, max TLP — R20 showed the
// 4-way ILP variant starved occupancy) + 3 W transposes riding free as
// trailing blocks (both regions are low-LDS/low-VGPR: no interference).
// cursor must be zeroed by the preceding memset (atomics race otherwise).
// ---------------------------------------------------------------------------
__global__ __launch_bounds__(256) void prep_scatter_kernel(
    const float* __restrict__ W0, const float* __restrict__ W1,
    const float* __restrict__ W2, const int* __restrict__ ei,
    _Float16* __restrict__ WT0, _Float16* __restrict__ WT1,
    _Float16* __restrict__ WT2, int* __restrict__ cursor,
    unsigned short* __restrict__ csr_src) {
  __shared__ float tile[32][33];
  const int bid = blockIdx.x;
  if (bid < EDGE_BLK) {
    int e = bid * 256 + threadIdx.x;
    if (e < E_TOTAL) {
      int s, d;
      if (e < N_EDGES) {
        s = ei[e];
        d = ei[N_EDGES + e];
      } else {
        s = d = e - N_EDGES;
      }
      int pos = atomicAdd(&cursor[d], 1);
      csr_src[(size_t)d * BKT + pos] = (unsigned short)s;
    }
  } else {
    const int sub = bid - EDGE_BLK; // 0..191
    const float* W = (sub < 64) ? W0 : (sub < 128) ? W1 : W2;
    _Float16* WT = (sub < 64) ? WT0 : (sub < 128) ? WT1 : WT2;
    const int s6 = sub & 63;
    const int bx = (s6 & 7) * 32, by = (s6 >> 3) * 32;
    const int tx = threadIdx.x & 31, ty = threadIdx.x >> 5;
#pragma unroll
    for (int i = 0; i < 32; i += 8)
      tile[ty + i][tx] = W[(size_t)(by + ty + i) * 256 + bx + tx];
    __syncthreads();
#pragma unroll
    for (int i = 0; i < 32; i += 8)
      WT[(size_t)(bx + ty + i) * 256 + by + tx] = (_Float16)tile[tx][ty + i];
  }
}

// ---------------------------------------------------------------------------
// Fused MFMA GEMM + attention epilogue. AF16=false: A is f32 (layer 0);
// staged via reg-load -> (after MFMA cluster, latency hidden) cvt+ds_write.
// BM=64, BN=256, BK=32, 8 K-steps; 4 waves 2x2 (wave = 32x128 = 2x8 frags).
// B double-buffered via global_load_lds; stage k+1 issued before MFMA k.
// ---------------------------------------------------------------------------
template <int H, bool AF16>
__global__ __launch_bounds__(256) void gemm_att(
    const void* __restrict__ Ap, const _Float16* __restrict__ WT,
    const float* __restrict__ att_s, const float* __restrict__ att_d,
    _Float16* __restrict__ C, float* __restrict__ a_s, float* __restrict__ a_d,
    int M) {
  __shared__ _Float16 As[2][64 * 32];   // 4 KB each
  __shared__ _Float16 Bs[2][256 * 32];  // 16 KB each
  const _Float16* A16 = (const _Float16*)Ap;
  const float* A32 = (const float*)Ap;
  const int t = threadIdx.x, lane = t & 63, w = t >> 6;
  const int wr = w & 1, wc = w >> 1;
  const int row0 = blockIdx.x * 64;
  const int fr = lane & 15, fg = lane >> 4;
  const int srow = lane >> 2, sk = (lane & 3) * 8;
  const int arow = t >> 2, ak = (t & 3) * 8; // f32 A staging coords (256 thr)

  f32x4 acc[2][8] = {};
  int cur = 0;
  float4 ar0, ar1; // in-flight f32 A data (AF16=false)

#define STAGE_B(buf, k0)                                                      \
  do {                                                                        \
    gl_lds16(WT + (size_t)(w * 64 + srow) * 256 + (k0) + sk,                  \
             &Bs[buf][w * 2048]);                                             \
    gl_lds16(WT + (size_t)(w * 64 + 16 + srow) * 256 + (k0) + sk,             \
             &Bs[buf][w * 2048 + 512]);                                       \
    gl_lds16(WT + (size_t)(w * 64 + 32 + srow) * 256 + (k0) + sk,             \
             &Bs[buf][w * 2048 + 1024]);                                      \
    gl_lds16(WT + (size_t)(w * 64 + 48 + srow) * 256 + (k0) + sk,             \
             &Bs[buf][w * 2048 + 1536]);                                      \
  } while (0)

#define STAGE_A16(buf, k0)                                                    \
  gl_lds16(A16 + (size_t)(row0 + w * 16 + srow) * 256 + (k0) + sk,            \
           &As[buf][w * 512])

#define LOAD_A32(k0)                                                          \
  do {                                                                        \
    if (row0 + arow < M) {                                                    \
      ar0 = *(const float4*)(A32 + (size_t)(row0 + arow) * 256 + (k0) + ak);  \
      ar1 = *(const float4*)(A32 + (size_t)(row0 + arow) * 256 + (k0) + ak + 4);\
    } else {                                                                  \
      ar0 = make_float4(0.f, 0.f, 0.f, 0.f);                                  \
      ar1 = make_float4(0.f, 0.f, 0.f, 0.f);                                  \
    }                                                                         \
  } while (0)

#define WRITE_A32(buf)                                                        \
  do {                                                                        \
    f16x8 v;                                                                  \
    v[0] = (_Float16)ar0.x; v[1] = (_Float16)ar0.y;                           \
    v[2] = (_Float16)ar0.z; v[3] = (_Float16)ar0.w;                           \
    v[4] = (_Float16)ar1.x; v[5] = (_Float16)ar1.y;                           \
    v[6] = (_Float16)ar1.z; v[7] = (_Float16)ar1.w;                           \
    *(f16x8*)&As[buf][arow * 32 + ak] = v;                                    \
  } while (0)

  if constexpr (AF16) {
    STAGE_A16(0, 0);
  } else {
    LOAD_A32(0);
    WRITE_A32(0);
  }
  STAGE_B(0, 0);
  __syncthreads(); // stage 0 landed (vmcnt + lgkm drain)

  for (int kt = 0; kt < 8; kt++) {
    if (kt < 7) {
      if constexpr (AF16) STAGE_A16(cur ^ 1, (kt + 1) * 32);
      else LOAD_A32((kt + 1) * 32); // loads fly during MFMA below
      STAGE_B(cur ^ 1, (kt + 1) * 32);
    }
    f16x8 af[2], bf[8];
#pragma unroll
    for (int mi = 0; mi < 2; mi++)
      af[mi] = *(const f16x8*)&As[cur][(wr * 32 + mi * 16 + fr) * 32 + fg * 8];
#pragma unroll
    for (int ni = 0; ni < 8; ni++)
      bf[ni] = *(const f16x8*)&Bs[cur][(wc * 128 + ni * 16 + fr) * 32 + fg * 8];
#pragma unroll
    for (int mi = 0; mi < 2; mi++)
#pragma unroll
      for (int ni = 0; ni < 8; ni++)
        acc[mi][ni] = __builtin_amdgcn_mfma_f32_16x16x32_f16(af[mi], bf[ni], acc[mi][ni], 0, 0, 0);
    if constexpr (!AF16) {
      if (kt < 7) WRITE_A32(cur ^ 1); // f32 loads landed under MFMA
    }
    __syncthreads(); // drains vmcnt+lgkm: next stage complete, LDS reads done
    cur ^= 1;
  }
#undef STAGE_B
#undef STAGE_A16
#undef LOAD_A32
#undef WRITE_A32

  float as_c[8], ad_c[8];
#pragma unroll
  for (int ni = 0; ni < 8; ni++) {
    int c = wc * 128 + ni * 16 + fr;
    as_c[ni] = att_s[c];
    ad_c[ni] = att_d[c];
  }

#pragma unroll
  for (int mi = 0; mi < 2; mi++) {
#pragma unroll
    for (int reg = 0; reg < 4; reg++) {
      const int r = row0 + wr * 32 + mi * 16 + fg * 4 + reg;
      const bool valid = r < M;
      if (valid) {
#pragma unroll
        for (int ni = 0; ni < 8; ni++)
          C[(size_t)r * 256 + wc * 128 + ni * 16 + fr] = (_Float16)acc[mi][ni][reg];
      }
      float s0 = 0.f, s1 = 0.f, d0 = 0.f, d1 = 0.f;
#pragma unroll
      for (int ni = 0; ni < 4; ni++) {
        s0 = fmaf(acc[mi][ni][reg], as_c[ni], s0);
        d0 = fmaf(acc[mi][ni][reg], ad_c[ni], d0);
        s1 = fmaf(acc[mi][ni + 4][reg], as_c[ni + 4], s1);
        d1 = fmaf(acc[mi][ni + 4][reg], ad_c[ni + 4], d1);
      }
#pragma unroll
      for (int off = 1; off < 16; off <<= 1) {
        s0 += __shfl_xor(s0, off, 64);
        d0 += __shfl_xor(d0, off, 64);
        s1 += __shfl_xor(s1, off, 64);
        d1 += __shfl_xor(d1, off, 64);
      }
      if constexpr (H == 4) {
        if (fr == 0 && valid) {
          a_s[(size_t)r * 4 + wc * 2 + 0] = s0;
          a_s[(size_t)r * 4 + wc * 2 + 1] = s1;
          a_d[(size_t)r * 4 + wc * 2 + 0] = d0;
          a_d[(size_t)r * 4 + wc * 2 + 1] = d1;
        }
      } else {
        if (fr == 0) {
          float* L = (float*)As; // safe: last loop barrier covers LDS reads
          L[(r - row0) * 4 + wc * 2 + 0] = s0 + s1;
          L[(r - row0) * 4 + wc * 2 + 1] = d0 + d1;
        }
      }
    }
  }
  if constexpr (H == 1) {
    __syncthreads();
    float* L = (float*)As;
    if (t < 64 && row0 + t < M) {
      a_s[row0 + t] = L[t * 4 + 0] + L[t * 4 + 2];
      a_d[row0 + t] = L[t * 4 + 1] + L[t * 4 + 3];
    }
  }
}

// ---------------------------------------------------------------------------
// SINGLE-PASS segment softmax + weighted gather; u16 bucket edge list.
// ---------------------------------------------------------------------------
template <int H, bool ELU_OUT, bool OUT_F16>
__global__ __launch_bounds__(256, 8) void aggregate_kernel(
    const _Float16* __restrict__ XH16, const float* __restrict__ a_s,
    const float* __restrict__ a_d, const int* __restrict__ cursor,
    const unsigned short* __restrict__ csr_src, const float* __restrict__ bias,
    void* __restrict__ outp) {
  const int t = threadIdx.x;
  const int lane = t & 63, w = t >> 6;
  const int d = blockIdx.x * 4 + w;
  const size_t e0 = (size_t)d * BKT;
  const int deg = cursor[d];
  const int li = lane & 15;
  const int h4 = (H == 4) ? (lane >> 4) : 0;
  const float adv = (H == 4) ? a_d[(size_t)d * 4 + h4] : a_d[d];

  float dnp = 0.f;
  float acc0 = 0.f, acc1 = 0.f, acc2 = 0.f, acc3 = 0.f;
  for (int base = 0; base < deg; base += 16) {
    const int cnt = min(16, deg - base);
    int s_cur = 0;
    float p = 0.f;
    if (li < cnt) {
      s_cur = csr_src[e0 + base + li];
      float e = ((H == 4) ? a_s[(size_t)s_cur * 4 + h4] : a_s[s_cur]) + adv;
      e = e > 0.f ? e : 0.2f * e;
      p = __expf(e);
    }
    dnp += p;
#define GAT_BODY(j)                                                           \
  {                                                                           \
    int sj = __builtin_amdgcn_readfirstlane(__shfl(s_cur, (j), 64));          \
    float alj = __shfl(p, (lane & 48) + (j), 64);                             \
    f16x4 raw = *(const f16x4*)(XH16 + (size_t)sj * 256 + lane * 4);          \
    acc0 = fmaf(alj, (float)raw[0], acc0);                                    \
    acc1 = fmaf(alj, (float)raw[1], acc1);                                    \
    acc2 = fmaf(alj, (float)raw[2], acc2);                                    \
    acc3 = fmaf(alj, (float)raw[3], acc3);                                    \
  }
    if (cnt == 16) {
#pragma unroll
      for (int j = 0; j < 16; j++) GAT_BODY(j)
    } else {
      for (int j = 0; j < cnt; j++) GAT_BODY(j)
    }
#undef GAT_BODY
  }
#pragma unroll
  for (int off = 1; off < 16; off <<= 1) dnp += __shfl_xor(dnp, off, 64);
  const float inv = 1.f / (dnp + 1e-16f);

  float4 bv = *(const float4*)&bias[lane * 4];
  float v0 = fmaf(acc0, inv, bv.x), v1 = fmaf(acc1, inv, bv.y);
  float v2 = fmaf(acc2, inv, bv.z), v3 = fmaf(acc3, inv, bv.w);
  if constexpr (ELU_OUT) {
    v0 = v0 > 0.f ? v0 : (__expf(v0) - 1.f);
    v1 = v1 > 0.f ? v1 : (__expf(v1) - 1.f);
    v2 = v2 > 0.f ? v2 : (__expf(v2) - 1.f);
    v3 = v3 > 0.f ? v3 : (__expf(v3) - 1.f);
  }
  if constexpr (OUT_F16) {
    _Float16* out = (_Float16*)outp;
    f16x4 ov;
    ov[0] = (_Float16)v0; ov[1] = (_Float16)v1;
    ov[2] = (_Float16)v2; ov[3] = (_Float16)v3;
    *(f16x4*)(out + (size_t)d * 256 + lane * 4) = ov;
  } else {
    float* out = (float*)outp;
    *(float4*)(out + (size_t)d * 256 + lane * 4) = make_float4(v0, v1, v2, v3);
  }
}

// ---------------------------------------------------------------------------
extern "C" void kernel_launch(void* const* d_in, const int* in_sizes, int n_in,
                              void* d_out, int out_size, void* d_ws, size_t ws_size,
                              hipStream_t stream) {
  const float* x = (const float*)d_in[0];
  const int* ei = (const int*)d_in[1];
  const float* W0 = (const float*)d_in[2];
  const float* as0 = (const float*)d_in[3];
  const float* ad0 = (const float*)d_in[4];
  const float* b0 = (const float*)d_in[5];
  const float* W1 = (const float*)d_in[6];
  const float* as1 = (const float*)d_in[7];
  const float* ad1 = (const float*)d_in[8];
  const float* b1 = (const float*)d_in[9];
  const float* W2 = (const float*)d_in[10];
  const float* as2 = (const float*)d_in[11];
  const float* ad2 = (const float*)d_in[12];
  const float* b2 = (const float*)d_in[13];
  float* out = (float*)d_out;

  char* p = (char*)d_ws;
  _Float16* XH16 = (_Float16*)p;
  p += (size_t)N_NODES * 256 * 2; // 25.6 MB
  _Float16* H16 = (_Float16*)p;
  p += (size_t)N_NODES * 256 * 2; // 25.6 MB
  _Float16* WT0 = (_Float16*)p;
  p += 256 * 256 * 2;
  _Float16* WT1 = (_Float16*)p;
  p += 256 * 256 * 2;
  _Float16* WT2 = (_Float16*)p;
  p += 256 * 256 * 2;
  float* a_s = (float*)p;
  p += (size_t)N_NODES * 4 * 4;
  float* a_d = (float*)p;
  p += (size_t)N_NODES * 4 * 4;
  int* cursor = (int*)p;
  p += (size_t)N_NODES * 4;
  unsigned short* csr_src = (unsigned short*)p;
  p += (size_t)N_NODES * BKT * 2; // 9.6 MB u16 buckets

  // cursor must be zero before the scatter's atomics
  hipMemsetAsync(cursor, 0, (size_t)N_NODES * 4, stream);

  // scatter (1 edge/thread, max TLP) + W transposes riding in trailing blocks
  prep_scatter_kernel<<<EDGE_BLK + 192, 256, 0, stream>>>(
      W0, W1, W2, ei, WT0, WT1, WT2, cursor, csr_src);

  const int ngrid = N_NODES / 4; // 12500

  // layer 0 (A = f32 x, direct)
  gemm_att<4, false><<<NTILES, 256, 0, stream>>>(x, WT0, as0, ad0, XH16, a_s, a_d, N_NODES);
  aggregate_kernel<4, true, true><<<ngrid, 256, 0, stream>>>(
      XH16, a_s, a_d, cursor, csr_src, b0, H16);
  // layer 1
  gemm_att<4, true><<<NTILES, 256, 0, stream>>>(H16, WT1, as1, ad1, XH16, a_s, a_d, N_NODES);
  aggregate_kernel<4, true, true><<<ngrid, 256, 0, stream>>>(
      XH16, a_s, a_d, cursor, csr_src, b1, H16);
  // layer 2
  gemm_att<1, true><<<NTILES, 256, 0, stream>>>(H16, WT2, as2, ad2, XH16, a_s, a_d, N_NODES);
  aggregate_kernel<1, false, false><<<ngrid, 256, 0, stream>>>(
      XH16, a_s, a_d, cursor, csr_src, b2, out);
}